// Round 12
// baseline (118.745 us; speedup 1.0000x reference)
//
#include <hip/hip_runtime.h>
#include <hip/hip_bf16.h>

#define DIM 128
#define SEQ 8192
#define NSPLIT 12
#define SCALE_L2E 0.1275325340249306f  // (1/sqrt(128)) * log2(e)
#define PSTR 72            // P LDS row stride in shorts (r6/r11-proven)

// ws layout (bytes): opb bf16 [NSPLIT][SEQ][DIM] | lp f32 [NSPLIT][SEQ] | Kst | Vst
#define OPB_BYTES ((size_t)NSPLIT * SEQ * DIM * 2)     // 25165824
#define LP_BYTE   OPB_BYTES
#define KST_BYTE  (LP_BYTE + (size_t)NSPLIT * SEQ * 4) // 25559040
#define VST_BYTE  (KST_BYTE + (size_t)SEQ * DIM * 2)   // 27656192
#define WS_NEED   (VST_BYTE + (size_t)SEQ * DIM * 2)   // 29753344 (~28.4 MB)

typedef __attribute__((ext_vector_type(8))) short short8;
typedef __attribute__((ext_vector_type(4))) float f32x4;
typedef __attribute__((ext_vector_type(16))) float f32x16;

__device__ __forceinline__ unsigned short f2bf(float f) {
  return __builtin_bit_cast(unsigned short, __float2bfloat16(f));
}
__device__ __forceinline__ unsigned int f2bf2(float a, float b) {
  return (unsigned int)f2bf(a) | ((unsigned int)f2bf(b) << 16);
}
__device__ __forceinline__ float bf2f(unsigned short u) {
  return __builtin_bit_cast(float, (unsigned int)u << 16);
}
__device__ __forceinline__ float fast_exp2(float x) {
#if __has_builtin(__builtin_amdgcn_exp2f)
  return __builtin_amdgcn_exp2f(x);
#else
  return exp2f(x);
#endif
}
__device__ __forceinline__ void async_cp16(const void* g, void* l) {
  __builtin_amdgcn_global_load_lds(
      (const __attribute__((address_space(1))) void*)g,
      (__attribute__((address_space(3))) void*)l, 16, 0, 0);
}

// ---------- pre-pass: fragment-order bf16 staging, 32-kv tiles contiguous ----------
// K_stage: tile32 t: chunk(16B) = t*512 + (cc*2+hi)*32 + n ;
//   value_j = K[t*32 + n][cc*16 + hi*8 + j]              (8 KB contiguous per tile)
// V_stage: tile32 t: chunk = t*512 + (dt*4 + c2*2 + hi)*32 + n ;
//   value_j = V[t*32 + c2*16 + hi*8 + j][dt*32 + n]      (8 KB contiguous per tile)
__global__ __launch_bounds__(256) void prep_kv(
    const float* __restrict__ K, const float* __restrict__ V,
    unsigned short* __restrict__ Kst, unsigned short* __restrict__ Vst) {
  const int t = threadIdx.x;
  if (blockIdx.x < 256) {
    __shared__ __align__(16) unsigned short klds[32 * 128];
    const int r0 = blockIdx.x * 32;           // one tile32
    #pragma unroll
    for (int i = 0; i < 4; i++) {
      int idx = i * 256 + t;
      int r  = idx >> 5;
      int c4 = (idx & 31) << 2;
      int g  = c4 >> 3;
      const float4 f = *(const float4*)(K + (size_t)(r0 + r) * DIM + c4);
      uint2 u = {f2bf2(f.x, f.y), f2bf2(f.z, f.w)};
      *(uint2*)&klds[r * 128 + ((g ^ (r & 7)) << 3) + (c4 & 7)] = u;
    }
    __syncthreads();
    const size_t base = (size_t)blockIdx.x * 512;
    #pragma unroll
    for (int e = 0; e < 2; e++) {
      int c  = e * 256 + t;
      int n  = c & 31;
      int hi = (c >> 5) & 1;
      int cc = c >> 6;
      int g  = cc * 2 + hi;
      uint4 u = *(const uint4*)&klds[n * 128 + ((g ^ (n & 7)) << 3)];
      *(uint4*)&Kst[(base + (size_t)g * 32 + n) * 8] = u;
    }
  } else {
    int c    = (blockIdx.x - 256) * 256 + t;  // 0..131071
    int n    = c & 31;
    int hi   = (c >> 5) & 1;
    int c2   = (c >> 6) & 3;
    int dt   = (c >> 8) & 3;
    int tile = c >> 10;                       // 64-row tile
    const float* src = V + (size_t)(tile * 64 + c2 * 16 + hi * 8) * DIM + dt * 32 + n;
    float v[8];
    #pragma unroll
    for (int j = 0; j < 8; j++) v[j] = src[(size_t)j * DIM];
    uint4 u;
    u.x = f2bf2(v[0], v[1]); u.y = f2bf2(v[2], v[3]);
    u.z = f2bf2(v[4], v[5]); u.w = f2bf2(v[6], v[7]);
    size_t oc = ((((size_t)(tile * 2 + (c2 >> 1)) * 4 + dt) * 2 + (c2 & 1)) * 2 + hi) * 32 + n;
    *(uint4*)&Vst[oc * 8] = u;
  }
}

// ---------- main: r11 structure, 12 uneven splits -> 768 blocks = 3 blocks/CU ----------
// grid (x=8, y=96): XCD = id%8 = x. y<64: split=x (12 tile64s), qtile=y.
// y>=64: split=8+(x>>1) (8 tile64s), qtile=(y-64)*2+(x&1).
// Per-XCD K/V working set ~640 KB (L2-resident). Per-CU work uniform (32 tile-iters).
// LDS: kt 16K + vt 16K + pt 18K = 51200 B -> 3 blocks/CU = 12 waves/CU.
__global__ __launch_bounds__(256, 3) void attn_main(
    const float* __restrict__ Q, const unsigned short* __restrict__ Kst,
    const unsigned short* __restrict__ Vst,
    unsigned short* __restrict__ opb, float* __restrict__ lp) {
  __shared__ __align__(16) unsigned short kt[8192];       // two tile32s (16 KB)
  __shared__ __align__(16) unsigned short vt[8192];
  __shared__ __align__(16) unsigned short pt[4][32 * PSTR];

  const int tid  = threadIdx.x;
  const int wave = tid >> 6;
  const int lane = tid & 63;
  const int m    = lane & 31;
  const int hi   = lane >> 5;

  const int gx = blockIdx.x, gy = blockIdx.y;
  int split, qtile;
  if (gy < 64) { split = gx;             qtile = gy; }
  else         { split = 8 + (gx >> 1);  qtile = (gy - 64) * 2 + (gx & 1); }
  const int ntile64  = (split < 8) ? 12 : 8;
  const int tstart64 = (split < 8) ? split * 12 : 96 + (split - 8) * 8;
  const int qbase = qtile * 128 + wave * 32;

  // Q A-frags, pre-scaled by SCALE*log2e: qf[cc][j] = Q[qbase+m][cc*16+hi*8+j]*c
  short8 qf[8];
  {
    const float* qrow = Q + (size_t)(qbase + m) * DIM + hi * 8;
    #pragma unroll
    for (int cc = 0; cc < 8; cc++) {
      float4 a = *(const float4*)(qrow + cc * 16);
      float4 b = *(const float4*)(qrow + cc * 16 + 4);
      short8 v;
      unsigned int u0 = f2bf2(a.x * SCALE_L2E, a.y * SCALE_L2E);
      unsigned int u1 = f2bf2(a.z * SCALE_L2E, a.w * SCALE_L2E);
      unsigned int u2 = f2bf2(b.x * SCALE_L2E, b.y * SCALE_L2E);
      unsigned int u3 = f2bf2(b.z * SCALE_L2E, b.w * SCALE_L2E);
      v[0] = (short)(u0 & 0xffff); v[1] = (short)(u0 >> 16);
      v[2] = (short)(u1 & 0xffff); v[3] = (short)(u1 >> 16);
      v[4] = (short)(u2 & 0xffff); v[5] = (short)(u2 >> 16);
      v[6] = (short)(u3 & 0xffff); v[7] = (short)(u3 >> 16);
      qf[cc] = v;
    }
  }

  float lsum[16];
  f32x16 accO[4];
  #pragma unroll
  for (int r = 0; r < 16; r++) lsum[r] = 0.f;
  #pragma unroll
  for (int dt = 0; dt < 4; dt++)
    #pragma unroll
    for (int r = 0; r < 16; r++) accO[dt][r] = 0.f;

  unsigned short* ptw = &pt[wave][0];
  const int tbase32 = tstart64 * 2;

  for (int it = 0; it < ntile64; it++) {
    const unsigned short* ks = Kst + (size_t)(tbase32 + it * 2) * 4096;
    const unsigned short* vs = Vst + (size_t)(tbase32 + it * 2) * 4096;
    __syncthreads();  // prior tile consumed before DMA overwrites
    #pragma unroll
    for (int i = 0; i < 4; i++) {
      int ch = wave * 4 + i;  // 16 x 1KB chunks each for K and V
      async_cp16(ks + ch * 512 + lane * 8, (char*)kt + ch * 1024);
      async_cp16(vs + ch * 512 + lane * 8, (char*)vt + ch * 1024);
    }
    __syncthreads();  // vmcnt drain before use

    // ---- S = Q K^T : two 32-kv halves, 16 MFMA ----
    f32x16 accS[2];
    #pragma unroll
    for (int kt2 = 0; kt2 < 2; kt2++) {
      f32x16 acc;
      #pragma unroll
      for (int r = 0; r < 16; r++) acc[r] = 0.f;
      #pragma unroll
      for (int cc = 0; cc < 8; cc++) {
        short8 b = *(const short8*)&kt[kt2 * 4096 + ((cc * 2 + hi) * 32 + m) * 8];
        acc = __builtin_amdgcn_mfma_f32_32x32x16_bf16(qf[cc], b, acc, 0, 0, 0);
      }
      accS[kt2] = acc;
    }

    // ---- p = exp2(s) (scale pre-folded); write P [32q][64kv] stride 72 ----
    #pragma unroll
    for (int kt2 = 0; kt2 < 2; kt2++) {
      #pragma unroll
      for (int reg = 0; reg < 16; reg++) {
        int row = (reg & 3) + 8 * (reg >> 2) + 4 * hi;
        float p = fast_exp2(accS[kt2][reg]);
        lsum[reg] += p;
        ptw[row * PSTR + kt2 * 32 + m] = f2bf(p);
      }
    }

    // ---- P A-frags ----
    short8 ap[4];
    #pragma unroll
    for (int g = 0; g < 4; g++)
      ap[g] = *(const short8*)&ptw[m * PSTR + g * 16 + hi * 8];

    // ---- O += P V : 16 MFMA ----
    #pragma unroll
    for (int dt = 0; dt < 4; dt++) {
      #pragma unroll
      for (int g = 0; g < 4; g++) {
        short8 b = *(const short8*)&vt[(g >> 1) * 4096 +
                                       ((dt * 4 + (g & 1) * 2 + hi) * 32 + m) * 8];
        accO[dt] = __builtin_amdgcn_mfma_f32_32x32x16_bf16(ap[g], b, accO[dt], 0, 0, 0);
      }
    }
  }

  // ---- epilogue: reduce l over 32-lane col group; store bf16 O-partials + l ----
  unsigned short* op = opb + (size_t)split * SEQ * DIM;
  float* lps = lp + (size_t)split * SEQ;
  #pragma unroll
  for (int reg = 0; reg < 16; reg++) {
    float l = lsum[reg];
    l += __shfl_xor(l, 1);
    l += __shfl_xor(l, 2);
    l += __shfl_xor(l, 4);
    l += __shfl_xor(l, 8);
    l += __shfl_xor(l, 16);
    int qrow = qbase + (reg & 3) + 8 * (reg >> 2) + 4 * hi;
    #pragma unroll
    for (int dt = 0; dt < 4; dt++)
      op[(size_t)qrow * DIM + dt * 32 + m] = f2bf(accO[dt][reg]);
    if (m == 0) lps[qrow] = l;
  }
}

// ---------- combine: O = (sum_s o_s) / (sum_s l_s), bf16 partials ----------
__global__ __launch_bounds__(256) void attn_combine(
    const unsigned short* __restrict__ opb, const float* __restrict__ lp,
    float* __restrict__ O) {
  int t = blockIdx.x * 256 + threadIdx.x;  // 262144 threads, 4 outputs each
  int qrow = t >> 5;
  int c4   = (t & 31) << 2;
  float denom = 0.f;
  #pragma unroll
  for (int s = 0; s < NSPLIT; s++) denom += lp[(size_t)s * SEQ + qrow];
  float4 acc = {0.f, 0.f, 0.f, 0.f};
  #pragma unroll
  for (int s = 0; s < NSPLIT; s++) {
    ushort4 u = *(const ushort4*)&opb[((size_t)s * SEQ + qrow) * DIM + c4];
    acc.x += bf2f(u.x); acc.y += bf2f(u.y);
    acc.z += bf2f(u.z); acc.w += bf2f(u.w);
  }
  float inv = 1.f / denom;
  float4 out = {acc.x * inv, acc.y * inv, acc.z * inv, acc.w * inv};
  *(float4*)&O[(size_t)qrow * DIM + c4] = out;
}

// ---------- fallback (single-pass 16x16 kernel, used only if ws too small) ----------
#define KSTR 136
#define VSTR 72
#define FPSTR 72
__global__ __launch_bounds__(256, 1) void attn_fwd_fb(
    const float* __restrict__ Q, const float* __restrict__ K,
    const float* __restrict__ V, float* __restrict__ O) {
  __shared__ __align__(16) unsigned short kt[64 * KSTR];
  __shared__ __align__(16) unsigned short vt[DIM * VSTR];
  __shared__ __align__(16) unsigned short pt[4][16 * FPSTR];
  const int tid = threadIdx.x, wave = tid >> 6, lane = tid & 63;
  const int l15 = lane & 15, quad = lane >> 4;
  const int qbase = blockIdx.x * 64 + wave * 16;
  short8 qf[4];
  {
    const float* qrow = Q + (size_t)(qbase + l15) * DIM + quad * 8;
    #pragma unroll
    for (int c = 0; c < 4; c++) {
      short8 v;
      #pragma unroll
      for (int j = 0; j < 8; j++) v[j] = (short)f2bf(qrow[c * 32 + j]);
      qf[c] = v;
    }
  }
  float lsum[4] = {0.f, 0.f, 0.f, 0.f};
  f32x4 o[8];
  const f32x4 fzero = {0.f, 0.f, 0.f, 0.f};
  #pragma unroll
  for (int d = 0; d < 8; d++) o[d] = fzero;
  unsigned short* pw = &pt[wave][0];
  for (int kv0 = 0; kv0 < SEQ; kv0 += 64) {
    __syncthreads();
    #pragma unroll
    for (int i = 0; i < 8; i++) {
      int idx = i * 256 + tid;
      int r = idx >> 5, c4 = (idx & 31) << 2;
      const float4 f = *(const float4*)(K + (size_t)(kv0 + r) * DIM + c4);
      uint2 u = {f2bf2(f.x, f.y), f2bf2(f.z, f.w)};
      *(uint2*)&kt[r * KSTR + c4] = u;
    }
    #pragma unroll
    for (int i = 0; i < 8; i++) {
      int idx = i * 256 + tid;
      int c = idx & 127, g = idx >> 7;
      const float* src = V + (size_t)(kv0 + 4 * g) * DIM + c;
      uint2 u = {f2bf2(src[0], src[DIM]), f2bf2(src[2 * DIM], src[3 * DIM])};
      *(uint2*)&vt[c * VSTR + 4 * g] = u;
    }
    __syncthreads();
    f32x4 s[4];
    #pragma unroll
    for (int blk = 0; blk < 4; blk++) {
      f32x4 acc = fzero;
      const unsigned short* kr = &kt[(blk * 16 + l15) * KSTR + quad * 8];
      #pragma unroll
      for (int c = 0; c < 4; c++)
        acc = __builtin_amdgcn_mfma_f32_16x16x32_bf16(qf[c], *(const short8*)&kr[c * 32], acc, 0, 0, 0);
      s[blk] = acc;
    }
    #pragma unroll
    for (int r = 0; r < 4; r++) {
      #pragma unroll
      for (int blk = 0; blk < 4; blk++) {
        float p = fast_exp2(s[blk][r] * SCALE_L2E);
        lsum[r] += p;
        pw[(quad * 4 + r) * FPSTR + blk * 16 + l15] = f2bf(p);
      }
    }
    short8 ap0 = *(const short8*)&pw[l15 * FPSTR + quad * 8];
    short8 ap1 = *(const short8*)&pw[l15 * FPSTR + 32 + quad * 8];
    #pragma unroll
    for (int d = 0; d < 8; d++) {
      const unsigned short* vr = &vt[(d * 16 + l15) * VSTR + quad * 8];
      o[d] = __builtin_amdgcn_mfma_f32_16x16x32_bf16(ap0, *(const short8*)&vr[0], o[d], 0, 0, 0);
      o[d] = __builtin_amdgcn_mfma_f32_16x16x32_bf16(ap1, *(const short8*)&vr[32], o[d], 0, 0, 0);
    }
  }
  #pragma unroll
  for (int r = 0; r < 4; r++) {
    float l = lsum[r];
    l += __shfl_xor(l, 1); l += __shfl_xor(l, 2);
    l += __shfl_xor(l, 4); l += __shfl_xor(l, 8);
    float inv = 1.f / l;
    float* orow = O + (size_t)(qbase + quad * 4 + r) * DIM + l15;
    #pragma unroll
    for (int d = 0; d < 8; d++) orow[d * 16] = o[d][r] * inv;
  }
}

extern "C" void kernel_launch(void* const* d_in, const int* in_sizes, int n_in,
                              void* d_out, int out_size, void* d_ws, size_t ws_size,
                              hipStream_t stream) {
  const float* Q = (const float*)d_in[0];
  const float* K = (const float*)d_in[1];
  const float* V = (const float*)d_in[2];
  float* O = (float*)d_out;
  if (ws_size >= WS_NEED) {
    char* ws = (char*)d_ws;
    unsigned short* opb = (unsigned short*)ws;
    float* lp           = (float*)(ws + LP_BYTE);
    unsigned short* Kst = (unsigned short*)(ws + KST_BYTE);
    unsigned short* Vst = (unsigned short*)(ws + VST_BYTE);
    hipLaunchKernelGGL(prep_kv, dim3(768), dim3(256), 0, stream, K, V, Kst, Vst);
    hipLaunchKernelGGL(attn_main, dim3(8, 96), dim3(256), 0, stream,
                       Q, Kst, Vst, opb, lp);
    hipLaunchKernelGGL(attn_combine, dim3(1024), dim3(256), 0, stream, opb, lp, O);
  } else {
    hipLaunchKernelGGL(attn_fwd_fb, dim3(SEQ / 64), dim3(256), 0, stream, Q, K, V, O);
  }
}